// Round 7
// baseline (2975.158 us; speedup 1.0000x reference)
//
#include <hip/hip_runtime.h>
#include <hip/hip_bf16.h>

#define N_ 1024
#define M_ 1152
#define L_ 32
#define NATSTRIDE (L_*M_)   // 36864
#define CONVK 129
#define OUTW 1024
#define NSTEP 31

typedef __attribute__((ext_vector_type(8))) short short8;
typedef __attribute__((ext_vector_type(4))) float f32x4;

__device__ __forceinline__ unsigned short f2bf(float f) {
    unsigned int u = __float_as_uint(f);
    u += 0x7FFFu + ((u >> 16) & 1u);   // round-to-nearest-even
    return (unsigned short)(u >> 16);
}
__device__ __forceinline__ float bf2f(unsigned short b) {
    return __uint_as_float(((unsigned int)b) << 16);
}

// Split convW[m][k][2] -> w0t[m][k], w1t[m][k] (bf16, k-contiguous = B^T layout)
__global__ __launch_bounds__(256) void build_wsplit(const float* __restrict__ convW,
                                                    unsigned short* __restrict__ w0t,
                                                    unsigned short* __restrict__ w1t) {
    int idx = blockIdx.x * blockDim.x + threadIdx.x;
    if (idx >= M_ * M_) return;
    int m = idx / M_;
    int k = idx - m * M_;
    const float* s = convW + (size_t)m * (2 * M_) + 2 * k;
    w0t[idx] = f2bf(s[0]);
    w1t[idx] = f2bf(s[1]);
}

// h0 = bf16(NATree[:, L-1, :])
__global__ __launch_bounds__(256) void build_h0(const float* __restrict__ nat,
                                                unsigned short* __restrict__ h0) {
    int idx = blockIdx.x * blockDim.x + threadIdx.x;
    if (idx >= N_ * M_) return;
    int n = idx / M_;
    int m = idx - n * M_;
    h0[idx] = f2bf(nat[(size_t)n * NATSTRIDE + (size_t)(L_ - 1) * M_ + m]);
}

// rbf[t][n][m] = bf16(NATree[n][30-t][m])  for t = 0..30
__global__ __launch_bounds__(256) void build_rbf(const float* __restrict__ nat,
                                                 unsigned short* __restrict__ rbf) {
    int idx = blockIdx.x * blockDim.x + threadIdx.x;   // one thread per 8 elems
    if (idx >= NSTEP * N_ * M_ / 8) return;
    int o = idx * 8;
    int t = o / (N_ * M_);
    int rem = o - t * (N_ * M_);
    int n = rem / M_;
    int m = rem - n * M_;
    int l = (NSTEP - 1) - t;
    const float* s = nat + (size_t)n * NATSTRIDE + (size_t)l * M_ + m;
    f32x4 v0 = *(const f32x4*)(s);
    f32x4 v1 = *(const f32x4*)(s + 4);
    short8 tt;
    #pragma unroll
    for (int e = 0; e < 4; ++e) {
        tt[e]     = (short)f2bf(v0[e]);
        tt[4 + e] = (short)f2bf(v1[e]);
    }
    *(short8*)(rbf + o) = tt;
}

// ---------------- Phase 1: Rpre = bf16( r_t @ W0^T + b ) for all t (unchanged R6) ----------------
#define P_BM 128
#define P_BN 128
#define P_BK 64
#define P_NT (M_ / P_BK)    // 18
#define P_LDP 72

__global__ __launch_bounds__(256) void rpre_gemm(
    const unsigned short* __restrict__ rbf,
    const unsigned short* __restrict__ w0t,
    const float* __restrict__ convb,
    unsigned short* __restrict__ rpre)
{
    __shared__ __align__(16) unsigned short As[2][P_BM * P_LDP];
    __shared__ __align__(16) unsigned short Bs[2][P_BN * P_LDP];

    int tid = threadIdx.x;
    int lane = tid & 63;
    int w = tid >> 6;
    int wr = w >> 1, wc = w & 1;
    int raw = blockIdx.y * 9 + blockIdx.x;
    int logical = (raw & 7) * 279 + (raw >> 3);   // 2232 = 8*279 bijective chunked swizzle
    int bx = logical % 9, by = logical / 9;
    int n0 = by * P_BM;
    int m0 = bx * P_BN;

    int lr = lane & 15;
    int lk = (lane >> 4) * 8;
    int srow = tid >> 3;
    int skcol = (tid & 7) * 8;

    f32x4 acc[4][4] = {};

    auto loadTile = [&](int it, short8 a[4], short8 b[4]) {
        int kb = it * P_BK;
        #pragma unroll
        for (int i = 0; i < 4; ++i) {
            int row = srow + i * 32;
            a[i] = *(const short8*)(rbf + (size_t)(n0 + row) * M_ + kb + skcol);
            b[i] = *(const short8*)(w0t + (size_t)(m0 + row) * M_ + kb + skcol);
        }
    };
    auto writeTile = [&](int buf, short8 a[4], short8 b[4]) {
        #pragma unroll
        for (int i = 0; i < 4; ++i) {
            *(short8*)&As[buf][(srow + i * 32) * P_LDP + skcol] = a[i];
            *(short8*)&Bs[buf][(srow + i * 32) * P_LDP + skcol] = b[i];
        }
    };

    {
        short8 a0[4], b0[4];
        loadTile(0, a0, b0);
        writeTile(0, a0, b0);
    }
    __syncthreads();

    int cur = 0;
    for (int it = 0; it < P_NT; ++it) {
        short8 a2[4], b2[4];
        if (it + 1 < P_NT) loadTile(it + 1, a2, b2);

        #pragma unroll
        for (int ks = 0; ks < P_BK; ks += 32) {
            short8 af[4], bf_[4];
            #pragma unroll
            for (int mi = 0; mi < 4; ++mi)
                af[mi] = *(const short8*)&As[cur][(wr * 64 + mi * 16 + lr) * P_LDP + ks + lk];
            #pragma unroll
            for (int ni = 0; ni < 4; ++ni)
                bf_[ni] = *(const short8*)&Bs[cur][(wc * 64 + ni * 16 + lr) * P_LDP + ks + lk];
            #pragma unroll
            for (int mi = 0; mi < 4; ++mi)
                #pragma unroll
                for (int ni = 0; ni < 4; ++ni)
                    acc[mi][ni] = __builtin_amdgcn_mfma_f32_16x16x32_bf16(
                        af[mi], bf_[ni], acc[mi][ni], 0, 0, 0);
        }
        if (it + 1 < P_NT) {
            writeTile(cur ^ 1, a2, b2);
            __syncthreads();
            cur ^= 1;
        }
    }

    #pragma unroll
    for (int mi = 0; mi < 4; ++mi) {
        #pragma unroll
        for (int ni = 0; ni < 4; ++ni) {
            int mloc = m0 + wc * 64 + ni * 16 + lr;
            float bias = convb[mloc];
            #pragma unroll
            for (int j = 0; j < 4; ++j) {
                int g = n0 + wr * 64 + mi * 16 + (lane >> 4) * 4 + j;
                rpre[(size_t)g * M_ + mloc] = f2bf(acc[mi][ni][j] + bias);
            }
        }
    }
}

// ---------------- Phase 3: persistent chain v2 ----------------
// 288 blocks = 16 rowgrps (64 rows) x 18 colgrps (64 cols); 69.6 KiB LDS -> 2 blocks/CU
// co-resident (288 <= 512 capacity, no deadlock). Per-rowgroup device-scope barrier.
// rg = bid%16 -> all 18 blocks of a rowgroup share one XCD under round-robin dispatch.
#define S_BM 64
#define S_BN 64
#define S_BK 128
#define S_NT (M_ / S_BK)    // 9
#define S_LDP 136

__global__ __launch_bounds__(256, 2) void chain_kernel(
    const unsigned short* __restrict__ w1t,
    const unsigned short* __restrict__ rpre,
    const unsigned short* __restrict__ rbf,
    const float* __restrict__ x,
    unsigned short* __restrict__ h0buf,     // holds h_0 on entry (parity 0)
    unsigned short* __restrict__ h1buf,     // parity 1
    float* __restrict__ res,
    unsigned int* __restrict__ bar)         // 16 counters, zeroed per launch
{
    __shared__ __align__(16) unsigned short As[2][S_BM * S_LDP];
    __shared__ __align__(16) unsigned short Bs[2][S_BN * S_LDP];

    int tid = threadIdx.x;
    int lane = tid & 63;
    int w = tid >> 6;
    int wr = w >> 1, wc = w & 1;            // 2x2 waves of 32x32
    int bid = blockIdx.x;
    int rg = bid & 15;                      // rowgroup 0..15 (fixed XCD = rg%8)
    int cg = bid >> 4;                      // colgroup 0..17
    int n0 = rg * S_BM;
    int m0 = cg * S_BN;
    int lr = lane & 15;
    int lk = (lane >> 4) * 8;
    int srow = tid >> 4;                    // 16 rows per pass, 4 passes
    int skcol = (tid & 15) * 8;

    for (int t = 0; t < NSTEP; ++t) {
        const unsigned short* hin  = (t & 1) ? h1buf : h0buf;
        unsigned short*       hout = (t & 1) ? h0buf : h1buf;
        const unsigned short* rpre_t = rpre + (size_t)t * N_ * M_;
        const unsigned short* rbf_t  = rbf  + (size_t)t * N_ * M_;
        int final_step = (t == NSTEP - 1);

        f32x4 acc[2][2] = {};

        auto loadTile = [&](int it, short8 a[4], short8 b[4]) {
            int kb = it * S_BK;
            #pragma unroll
            for (int i = 0; i < 4; ++i) {
                int row = srow + i * 16;
                a[i] = *(const short8*)(hin + (size_t)(n0 + row) * M_ + kb + skcol);
                b[i] = *(const short8*)(w1t + (size_t)(m0 + row) * M_ + kb + skcol);
            }
        };
        auto writeTile = [&](int buf, short8 a[4], short8 b[4]) {
            #pragma unroll
            for (int i = 0; i < 4; ++i) {
                *(short8*)&As[buf][(srow + i * 16) * S_LDP + skcol] = a[i];
                *(short8*)&Bs[buf][(srow + i * 16) * S_LDP + skcol] = b[i];
            }
        };

        {
            short8 a0[4], b0[4];
            loadTile(0, a0, b0);
            writeTile(0, a0, b0);
        }
        __syncthreads();

        // early-issue epilogue operands: HBM/L3 latency hides under the K-loop
        unsigned short preR[2][2][4], rbfR[2][2][4];
        #pragma unroll
        for (int mi = 0; mi < 2; ++mi)
            #pragma unroll
            for (int ni = 0; ni < 2; ++ni) {
                int mloc = m0 + wc * 32 + ni * 16 + lr;
                #pragma unroll
                for (int j = 0; j < 4; ++j) {
                    int nloc = n0 + wr * 32 + mi * 16 + (lane >> 4) * 4 + j;
                    preR[mi][ni][j] = rpre_t[(size_t)nloc * M_ + mloc];
                    rbfR[mi][ni][j] = rbf_t[(size_t)nloc * M_ + mloc];
                }
            }

        int cur = 0;
        for (int it = 0; it < S_NT; ++it) {
            short8 a2[4], b2[4];
            if (it + 1 < S_NT) loadTile(it + 1, a2, b2);

            #pragma unroll
            for (int ks = 0; ks < S_BK; ks += 32) {
                short8 af[2], bf_[2];
                #pragma unroll
                for (int mi = 0; mi < 2; ++mi)
                    af[mi] = *(const short8*)&As[cur][(wr * 32 + mi * 16 + lr) * S_LDP + ks + lk];
                #pragma unroll
                for (int ni = 0; ni < 2; ++ni)
                    bf_[ni] = *(const short8*)&Bs[cur][(wc * 32 + ni * 16 + lr) * S_LDP + ks + lk];
                #pragma unroll
                for (int mi = 0; mi < 2; ++mi)
                    #pragma unroll
                    for (int ni = 0; ni < 2; ++ni)
                        acc[mi][ni] = __builtin_amdgcn_mfma_f32_16x16x32_bf16(
                            af[mi], bf_[ni], acc[mi][ni], 0, 0, 0);
            }
            if (it + 1 < S_NT) {
                writeTile(cur ^ 1, a2, b2);
                __syncthreads();
                cur ^= 1;
            }
        }

        #pragma unroll
        for (int mi = 0; mi < 2; ++mi) {
            #pragma unroll
            for (int ni = 0; ni < 2; ++ni) {
                int mloc = m0 + wc * 32 + ni * 16 + lr;
                #pragma unroll
                for (int j = 0; j < 4; ++j) {
                    int nloc = n0 + wr * 32 + mi * 16 + (lane >> 4) * 4 + j;
                    float pre = acc[mi][ni][j] + bf2f(preR[mi][ni][j]);
                    float hv = tanhf(pre) + bf2f(rbfR[mi][ni][j]);
                    if (final_step) {
                        res[(size_t)nloc * M_ + mloc] = tanhf(tanhf(hv) + x[(size_t)nloc * M_ + mloc]);
                    } else {
                        hout[(size_t)nloc * M_ + mloc] = f2bf(hv);
                    }
                }
            }
        }

        // per-rowgroup barrier (18 blocks), device-scope; skip after final step
        if (!final_step) {
            __threadfence();
            __syncthreads();
            if (tid == 0) {
                atomicAdd(&bar[rg], 1u);
                unsigned int target = 18u * (unsigned)(t + 1);
                while (__hip_atomic_load(&bar[rg], __ATOMIC_ACQUIRE,
                                         __HIP_MEMORY_SCOPE_AGENT) < target) {
                    __builtin_amdgcn_s_sleep(2);
                }
            }
            __syncthreads();
            __threadfence();
        }
    }
}

// out[n][j] = conv2b + sum_k res[n][j+k] * conv2W[k]
__global__ __launch_bounds__(256) void conv_out_kernel(
    const float* __restrict__ res, const float* __restrict__ w2,
    const float* __restrict__ b2, float* __restrict__ out)
{
    __shared__ float row[M_];
    __shared__ float wk[CONVK];
    int n = blockIdx.x;
    int tid = threadIdx.x;
    for (int i = tid; i < M_; i += 256) row[i] = res[(size_t)n * M_ + i];
    if (tid < CONVK) wk[tid] = w2[tid];
    __syncthreads();
    float b = b2[0];
    int j0 = tid * 4;
    float s0 = b, s1 = b, s2 = b, s3 = b;
    float r0 = row[j0], r1 = row[j0 + 1], r2 = row[j0 + 2], r3 = row[j0 + 3];
    for (int k = 0; k < CONVK; ++k) {
        float wv = wk[k];
        s0 += r0 * wv; s1 += r1 * wv; s2 += r2 * wv; s3 += r3 * wv;
        if (k < CONVK - 1) { r0 = r1; r1 = r2; r2 = r3; r3 = row[j0 + 4 + k]; }
    }
    float* o = out + (size_t)n * OUTW + j0;
    o[0] = s0; o[1] = s1; o[2] = s2; o[3] = s3;
}

extern "C" void kernel_launch(void* const* d_in, const int* in_sizes, int n_in,
                              void* d_out, int out_size, void* d_ws, size_t ws_size,
                              hipStream_t stream) {
    const float* NATree = (const float*)d_in[0];
    const float* x      = (const float*)d_in[1];
    const float* convW  = (const float*)d_in[2];
    const float* convb  = (const float*)d_in[3];
    const float* conv2W = (const float*)d_in[4];
    const float* conv2b = (const float*)d_in[5];
    float* out = (float*)d_out;

    char* ws = (char*)d_ws;
    size_t off = 0;
    auto alloc = [&](size_t bytes) {
        void* p = ws + off;
        off = (off + bytes + 255) & ~(size_t)255;
        return p;
    };
    unsigned short* w0t  = (unsigned short*)alloc((size_t)M_ * M_ * 2);
    unsigned short* w1t  = (unsigned short*)alloc((size_t)M_ * M_ * 2);
    unsigned short* hA   = (unsigned short*)alloc((size_t)N_ * M_ * 2);
    unsigned short* hB   = (unsigned short*)alloc((size_t)N_ * M_ * 2);
    unsigned short* rpre = (unsigned short*)alloc((size_t)NSTEP * N_ * M_ * 2);
    unsigned short* rbf  = (unsigned short*)alloc((size_t)NSTEP * N_ * M_ * 2);
    float*          res  = (float*)alloc((size_t)N_ * M_ * 4);
    unsigned int*   bar  = (unsigned int*)alloc(256);

    hipMemsetAsync(bar, 0, 256, stream);
    build_wsplit<<<(M_ * M_ + 255) / 256, 256, 0, stream>>>(convW, w0t, w1t);
    build_h0<<<(N_ * M_ + 255) / 256, 256, 0, stream>>>(NATree, hA);
    build_rbf<<<(NSTEP * N_ * M_ / 8 + 255) / 256, 256, 0, stream>>>(NATree, rbf);

    // Phase 1: all 31 r_t @ W0^T + b in one GEMM (M = 31744)
    rpre_gemm<<<dim3(M_ / P_BN, (NSTEP * N_) / P_BM), 256, 0, stream>>>(rbf, w0t, convb, rpre);

    // Phase 3: persistent chain (288 blocks, 2/CU co-resident; rowgroup barriers inside)
    chain_kernel<<<288, 256, 0, stream>>>(w1t, rpre, rbf, x, hA, hB, res, bar);

    conv_out_kernel<<<1024, 256, 0, stream>>>(res, conv2W, conv2b, out);
}

// Round 8
// 729.067 us; speedup vs baseline: 4.0808x; 4.0808x over previous
//
#include <hip/hip_runtime.h>
#include <hip/hip_bf16.h>

#define N_ 1024
#define M_ 1152
#define L_ 32
#define NATSTRIDE (L_*M_)   // 36864
#define CONVK 129
#define OUTW 1024
#define NSTEP 31

typedef __attribute__((ext_vector_type(8))) short short8;
typedef __attribute__((ext_vector_type(4))) float f32x4;
typedef unsigned long long u64;

__device__ __forceinline__ unsigned short f2bf(float f) {
    unsigned int u = __float_as_uint(f);
    u += 0x7FFFu + ((u >> 16) & 1u);   // round-to-nearest-even
    return (unsigned short)(u >> 16);
}
__device__ __forceinline__ float bf2f(unsigned short b) {
    return __uint_as_float(((unsigned int)b) << 16);
}

// Split convW[m][k][2] -> w0t[m][k], w1t[m][k] (bf16, k-contiguous = B^T layout)
__global__ __launch_bounds__(256) void build_wsplit(const float* __restrict__ convW,
                                                    unsigned short* __restrict__ w0t,
                                                    unsigned short* __restrict__ w1t) {
    int idx = blockIdx.x * blockDim.x + threadIdx.x;
    if (idx >= M_ * M_) return;
    int m = idx / M_;
    int k = idx - m * M_;
    const float* s = convW + (size_t)m * (2 * M_) + 2 * k;
    w0t[idx] = f2bf(s[0]);
    w1t[idx] = f2bf(s[1]);
}

// h0 = bf16(NATree[:, L-1, :])
__global__ __launch_bounds__(256) void build_h0(const float* __restrict__ nat,
                                                unsigned short* __restrict__ h0) {
    int idx = blockIdx.x * blockDim.x + threadIdx.x;
    if (idx >= N_ * M_) return;
    int n = idx / M_;
    int m = idx - n * M_;
    h0[idx] = f2bf(nat[(size_t)n * NATSTRIDE + (size_t)(L_ - 1) * M_ + m]);
}

// rbf[t][n][m] = bf16(NATree[n][30-t][m])  for t = 0..30
__global__ __launch_bounds__(256) void build_rbf(const float* __restrict__ nat,
                                                 unsigned short* __restrict__ rbf) {
    int idx = blockIdx.x * blockDim.x + threadIdx.x;   // one thread per 8 elems
    if (idx >= NSTEP * N_ * M_ / 8) return;
    int o = idx * 8;
    int t = o / (N_ * M_);
    int rem = o - t * (N_ * M_);
    int n = rem / M_;
    int m = rem - n * M_;
    int l = (NSTEP - 1) - t;
    const float* s = nat + (size_t)n * NATSTRIDE + (size_t)l * M_ + m;
    f32x4 v0 = *(const f32x4*)(s);
    f32x4 v1 = *(const f32x4*)(s + 4);
    short8 tt;
    #pragma unroll
    for (int e = 0; e < 4; ++e) {
        tt[e]     = (short)f2bf(v0[e]);
        tt[4 + e] = (short)f2bf(v1[e]);
    }
    *(short8*)(rbf + o) = tt;
}

// ---------------- Phase 1: Rpre = bf16( r_t @ W0^T + b ) for all t (unchanged R6) ----------------
#define P_BM 128
#define P_BN 128
#define P_BK 64
#define P_NT (M_ / P_BK)    // 18
#define P_LDP 72

__global__ __launch_bounds__(256) void rpre_gemm(
    const unsigned short* __restrict__ rbf,
    const unsigned short* __restrict__ w0t,
    const float* __restrict__ convb,
    unsigned short* __restrict__ rpre)
{
    __shared__ __align__(16) unsigned short As[2][P_BM * P_LDP];
    __shared__ __align__(16) unsigned short Bs[2][P_BN * P_LDP];

    int tid = threadIdx.x;
    int lane = tid & 63;
    int w = tid >> 6;
    int wr = w >> 1, wc = w & 1;
    int raw = blockIdx.y * 9 + blockIdx.x;
    int logical = (raw & 7) * 279 + (raw >> 3);   // 2232 = 8*279 bijective chunked swizzle
    int bx = logical % 9, by = logical / 9;
    int n0 = by * P_BM;
    int m0 = bx * P_BN;

    int lr = lane & 15;
    int lk = (lane >> 4) * 8;
    int srow = tid >> 3;
    int skcol = (tid & 7) * 8;

    f32x4 acc[4][4] = {};

    auto loadTile = [&](int it, short8 a[4], short8 b[4]) {
        int kb = it * P_BK;
        #pragma unroll
        for (int i = 0; i < 4; ++i) {
            int row = srow + i * 32;
            a[i] = *(const short8*)(rbf + (size_t)(n0 + row) * M_ + kb + skcol);
            b[i] = *(const short8*)(w0t + (size_t)(m0 + row) * M_ + kb + skcol);
        }
    };
    auto writeTile = [&](int buf, short8 a[4], short8 b[4]) {
        #pragma unroll
        for (int i = 0; i < 4; ++i) {
            *(short8*)&As[buf][(srow + i * 32) * P_LDP + skcol] = a[i];
            *(short8*)&Bs[buf][(srow + i * 32) * P_LDP + skcol] = b[i];
        }
    };

    {
        short8 a0[4], b0[4];
        loadTile(0, a0, b0);
        writeTile(0, a0, b0);
    }
    __syncthreads();

    int cur = 0;
    for (int it = 0; it < P_NT; ++it) {
        short8 a2[4], b2[4];
        if (it + 1 < P_NT) loadTile(it + 1, a2, b2);

        #pragma unroll
        for (int ks = 0; ks < P_BK; ks += 32) {
            short8 af[4], bf_[4];
            #pragma unroll
            for (int mi = 0; mi < 4; ++mi)
                af[mi] = *(const short8*)&As[cur][(wr * 64 + mi * 16 + lr) * P_LDP + ks + lk];
            #pragma unroll
            for (int ni = 0; ni < 4; ++ni)
                bf_[ni] = *(const short8*)&Bs[cur][(wc * 64 + ni * 16 + lr) * P_LDP + ks + lk];
            #pragma unroll
            for (int mi = 0; mi < 4; ++mi)
                #pragma unroll
                for (int ni = 0; ni < 4; ++ni)
                    acc[mi][ni] = __builtin_amdgcn_mfma_f32_16x16x32_bf16(
                        af[mi], bf_[ni], acc[mi][ni], 0, 0, 0);
        }
        if (it + 1 < P_NT) {
            writeTile(cur ^ 1, a2, b2);
            __syncthreads();
            cur ^= 1;
        }
    }

    #pragma unroll
    for (int mi = 0; mi < 4; ++mi) {
        #pragma unroll
        for (int ni = 0; ni < 4; ++ni) {
            int mloc = m0 + wc * 64 + ni * 16 + lr;
            float bias = convb[mloc];
            #pragma unroll
            for (int j = 0; j < 4; ++j) {
                int g = n0 + wr * 64 + mi * 16 + (lane >> 4) * 4 + j;
                rpre[(size_t)g * M_ + mloc] = f2bf(acc[mi][ni][j] + bias);
            }
        }
    }
}

// ---------------- Phase 3: persistent chain v3 ----------------
// 144 blocks = 16 rowgrps (64 rows) x 9 colgrps (128 cols); 54 KiB LDS, 1 block/CU.
// Rowgroup chains are fully independent; per-rowgroup barrier fan-in = 9.
// Barrier: padded counters (128B apart), RELAXED poll + RELAXED signal (ordering via
// __syncthreads' vmcnt(0) drain). h traffic via relaxed AGENT-scope atomics (coherent
// past the per-XCD L2s, mapping-agnostic). No fences, no L2 invalidate/writeback.
#define S_BM 64
#define S_BN 128
#define S_BK 64
#define S_NT (M_ / S_BK)    // 18
#define S_LDP 72
#define N_RG 16
#define N_CG 9

__global__ __launch_bounds__(256) void chain_kernel(
    const unsigned short* __restrict__ w1t,
    const unsigned short* __restrict__ rpre,
    const unsigned short* __restrict__ rbf,
    const float* __restrict__ x,
    unsigned short* h0buf,                  // holds h_0 on entry (parity 0)
    unsigned short* h1buf,                  // parity 1
    float* __restrict__ res,
    unsigned int* bar)                      // 16 counters, 128B apart, zeroed per launch
{
    __shared__ __align__(16) unsigned short As[2][S_BM * S_LDP];   // 18 KiB
    __shared__ __align__(16) unsigned short Bs[2][S_BN * S_LDP];   // 36 KiB

    int tid = threadIdx.x;
    int lane = tid & 63;
    int w = tid >> 6;
    int wr = w >> 1, wc = w & 1;            // wave tile: 32 rows x 64 cols
    int bid = blockIdx.x;
    int rg = bid & 15;
    int cg = bid >> 4;
    int n0 = rg * S_BM;
    int m0 = cg * S_BN;
    int lr = lane & 15;
    int lg = lane >> 4;
    int lk = lg * 8;
    int srow = tid >> 3;                    // 0..31
    int skcol = (tid & 7) * 8;

    auto ldA8 = [](const unsigned short* p) -> short8 {
        union { u64 q[2]; short8 v; } u;
        u.q[0] = __hip_atomic_load((const u64*)p,       __ATOMIC_RELAXED, __HIP_MEMORY_SCOPE_AGENT);
        u.q[1] = __hip_atomic_load((const u64*)(p + 4), __ATOMIC_RELAXED, __HIP_MEMORY_SCOPE_AGENT);
        return u.v;
    };

    for (int t = 0; t < NSTEP; ++t) {
        const unsigned short* hin  = (t & 1) ? h1buf : h0buf;
        unsigned short*       hout = (t & 1) ? h0buf : h1buf;
        const unsigned short* rpre_t = rpre + (size_t)t * N_ * M_;
        const unsigned short* rbf_t  = rbf  + (size_t)t * N_ * M_;
        int final_step = (t == NSTEP - 1);

        f32x4 acc[2][4] = {};

        auto loadTile = [&](int it, short8 a[2], short8 b[4]) {
            int kb = it * S_BK;
            #pragma unroll
            for (int i = 0; i < 2; ++i)
                a[i] = ldA8(hin + (size_t)(n0 + srow + i * 32) * M_ + kb + skcol);
            #pragma unroll
            for (int i = 0; i < 4; ++i)
                b[i] = *(const short8*)(w1t + (size_t)(m0 + srow + i * 32) * M_ + kb + skcol);
        };
        auto writeTile = [&](int buf, short8 a[2], short8 b[4]) {
            #pragma unroll
            for (int i = 0; i < 2; ++i)
                *(short8*)&As[buf][(srow + i * 32) * S_LDP + skcol] = a[i];
            #pragma unroll
            for (int i = 0; i < 4; ++i)
                *(short8*)&Bs[buf][(srow + i * 32) * S_LDP + skcol] = b[i];
        };

        {
            short8 a0[2], b0[4];
            loadTile(0, a0, b0);
            writeTile(0, a0, b0);
        }

        // early-issue epilogue operands (cached loads; latency hides under K-loop)
        unsigned short preR[2][4][4], rbfR[2][4][4];
        #pragma unroll
        for (int mi = 0; mi < 2; ++mi)
            #pragma unroll
            for (int ni = 0; ni < 4; ++ni) {
                int mloc = m0 + wc * 64 + ni * 16 + lr;
                #pragma unroll
                for (int j = 0; j < 4; ++j) {
                    int nloc = n0 + wr * 32 + mi * 16 + lg * 4 + j;
                    preR[mi][ni][j] = rpre_t[(size_t)nloc * M_ + mloc];
                    rbfR[mi][ni][j] = rbf_t[(size_t)nloc * M_ + mloc];
                }
            }
        __syncthreads();

        int cur = 0;
        for (int it = 0; it < S_NT; ++it) {
            short8 a2[2], b2[4];
            if (it + 1 < S_NT) loadTile(it + 1, a2, b2);

            #pragma unroll
            for (int ks = 0; ks < S_BK; ks += 32) {
                short8 af[2], bf_[4];
                #pragma unroll
                for (int mi = 0; mi < 2; ++mi)
                    af[mi] = *(const short8*)&As[cur][(wr * 32 + mi * 16 + lr) * S_LDP + ks + lk];
                #pragma unroll
                for (int ni = 0; ni < 4; ++ni)
                    bf_[ni] = *(const short8*)&Bs[cur][(wc * 64 + ni * 16 + lr) * S_LDP + ks + lk];
                #pragma unroll
                for (int mi = 0; mi < 2; ++mi)
                    #pragma unroll
                    for (int ni = 0; ni < 4; ++ni)
                        acc[mi][ni] = __builtin_amdgcn_mfma_f32_16x16x32_bf16(
                            af[mi], bf_[ni], acc[mi][ni], 0, 0, 0);
            }
            if (it + 1 < S_NT) {
                writeTile(cur ^ 1, a2, b2);
                __syncthreads();
                cur ^= 1;
            }
        }

        #pragma unroll
        for (int mi = 0; mi < 2; ++mi) {
            #pragma unroll
            for (int ni = 0; ni < 4; ++ni) {
                int mloc = m0 + wc * 64 + ni * 16 + lr;
                #pragma unroll
                for (int j = 0; j < 4; ++j) {
                    int nloc = n0 + wr * 32 + mi * 16 + lg * 4 + j;
                    float pre = acc[mi][ni][j] + bf2f(preR[mi][ni][j]);
                    float hv = tanhf(pre) + bf2f(rbfR[mi][ni][j]);
                    if (final_step) {
                        res[(size_t)nloc * M_ + mloc] = tanhf(tanhf(hv) + x[(size_t)nloc * M_ + mloc]);
                    } else {
                        __hip_atomic_store(&hout[(size_t)nloc * M_ + mloc], f2bf(hv),
                                           __ATOMIC_RELAXED, __HIP_MEMORY_SCOPE_AGENT);
                    }
                }
            }
        }

        if (!final_step) {
            __syncthreads();   // drains vmcnt(0) per wave -> all h stores at coherence point
            if (tid == 0) {
                __hip_atomic_fetch_add(&bar[rg << 5], 1u,
                                       __ATOMIC_RELAXED, __HIP_MEMORY_SCOPE_AGENT);
                unsigned int target = (unsigned)N_CG * (unsigned)(t + 1);
                while (__hip_atomic_load(&bar[rg << 5], __ATOMIC_RELAXED,
                                         __HIP_MEMORY_SCOPE_AGENT) < target) {
                    __builtin_amdgcn_s_sleep(1);
                }
            }
            __syncthreads();
        }
    }
}

// out[n][j] = conv2b + sum_k res[n][j+k] * conv2W[k]
__global__ __launch_bounds__(256) void conv_out_kernel(
    const float* __restrict__ res, const float* __restrict__ w2,
    const float* __restrict__ b2, float* __restrict__ out)
{
    __shared__ float row[M_];
    __shared__ float wk[CONVK];
    int n = blockIdx.x;
    int tid = threadIdx.x;
    for (int i = tid; i < M_; i += 256) row[i] = res[(size_t)n * M_ + i];
    if (tid < CONVK) wk[tid] = w2[tid];
    __syncthreads();
    float b = b2[0];
    int j0 = tid * 4;
    float s0 = b, s1 = b, s2 = b, s3 = b;
    float r0 = row[j0], r1 = row[j0 + 1], r2 = row[j0 + 2], r3 = row[j0 + 3];
    for (int k = 0; k < CONVK; ++k) {
        float wv = wk[k];
        s0 += r0 * wv; s1 += r1 * wv; s2 += r2 * wv; s3 += r3 * wv;
        if (k < CONVK - 1) { r0 = r1; r1 = r2; r2 = r3; r3 = row[j0 + 4 + k]; }
    }
    float* o = out + (size_t)n * OUTW + j0;
    o[0] = s0; o[1] = s1; o[2] = s2; o[3] = s3;
}

extern "C" void kernel_launch(void* const* d_in, const int* in_sizes, int n_in,
                              void* d_out, int out_size, void* d_ws, size_t ws_size,
                              hipStream_t stream) {
    const float* NATree = (const float*)d_in[0];
    const float* x      = (const float*)d_in[1];
    const float* convW  = (const float*)d_in[2];
    const float* convb  = (const float*)d_in[3];
    const float* conv2W = (const float*)d_in[4];
    const float* conv2b = (const float*)d_in[5];
    float* out = (float*)d_out;

    char* ws = (char*)d_ws;
    size_t off = 0;
    auto alloc = [&](size_t bytes) {
        void* p = ws + off;
        off = (off + bytes + 255) & ~(size_t)255;
        return p;
    };
    unsigned short* w0t  = (unsigned short*)alloc((size_t)M_ * M_ * 2);
    unsigned short* w1t  = (unsigned short*)alloc((size_t)M_ * M_ * 2);
    unsigned short* hA   = (unsigned short*)alloc((size_t)N_ * M_ * 2);
    unsigned short* hB   = (unsigned short*)alloc((size_t)N_ * M_ * 2);
    unsigned short* rpre = (unsigned short*)alloc((size_t)NSTEP * N_ * M_ * 2);
    unsigned short* rbf  = (unsigned short*)alloc((size_t)NSTEP * N_ * M_ * 2);
    float*          res  = (float*)alloc((size_t)N_ * M_ * 4);
    unsigned int*   bar  = (unsigned int*)alloc(4096);

    hipMemsetAsync(bar, 0, 4096, stream);
    build_wsplit<<<(M_ * M_ + 255) / 256, 256, 0, stream>>>(convW, w0t, w1t);
    build_h0<<<(N_ * M_ + 255) / 256, 256, 0, stream>>>(NATree, hA);
    build_rbf<<<(NSTEP * N_ * M_ / 8 + 255) / 256, 256, 0, stream>>>(NATree, rbf);

    // Phase 1: all 31 r_t @ W0^T + b in one GEMM (M = 31744)
    rpre_gemm<<<dim3(M_ / P_BN, (NSTEP * N_) / P_BM), 256, 0, stream>>>(rbf, w0t, convb, rpre);

    // Phase 3: persistent chain v3 (144 blocks, 1/CU; relaxed rowgroup barriers)
    chain_kernel<<<N_RG * N_CG, 256, 0, stream>>>(w1t, rpre, rbf, x, hA, hB, res, bar);

    conv_out_kernel<<<1024, 256, 0, stream>>>(res, conv2W, conv2b, out);
}